// Round 1
// baseline (613.061 us; speedup 1.0000x reference)
//
#include <hip/hip_runtime.h>

#define BG 64
#define NN 2048
#define MM 2048
#define CC 64
#define HH 128
#define NNZE 32768
#define TH 384  // 3*H

// ---------------- count: edges per (g,row), rows per (g,cluster) ----------------
__global__ __launch_bounds__(256) void count_kernel(const int* __restrict__ d_rows,
                                                    const int* __restrict__ d_index,
                                                    int* __restrict__ cnt_row,
                                                    int* __restrict__ cnt_clu) {
    int tid = blockIdx.x * 256 + threadIdx.x;
    if (tid < BG * NNZE) {
        int g = tid >> 15;  // NNZ = 2^15
        atomicAdd(&cnt_row[(g << 11) + d_rows[tid]], 1);
    } else {
        int i = tid - BG * NNZE;
        if (i < BG * MM) {
            int g = i >> 11;  // M = 2^11
            atomicAdd(&cnt_clu[(g << 6) + d_index[i]], 1);
        }
    }
}

// ---------------- per-graph exclusive scans (rows: 2048, clusters: 64) ----------------
__global__ __launch_bounds__(256) void scan_kernel(const int* __restrict__ cnt_row,
                                                   int* __restrict__ off_row,
                                                   const int* __restrict__ cnt_clu,
                                                   int* __restrict__ off_clu) {
    __shared__ int lsum[256];
    __shared__ int lclu[64];
    int g = blockIdx.x, t = threadIdx.x;
    const int* cr = cnt_row + g * MM;
    int* orw = off_row + g * MM;
    int loc[8];
    int s = 0;
#pragma unroll
    for (int i = 0; i < 8; i++) { loc[i] = cr[t * 8 + i]; s += loc[i]; }
    lsum[t] = s;
    if (t < 64) lclu[t] = cnt_clu[g * CC + t];
    __syncthreads();
    for (int d = 1; d < 256; d <<= 1) {
        int v = (t >= d) ? lsum[t - d] : 0;
        __syncthreads();
        lsum[t] += v;
        __syncthreads();
    }
    int base = lsum[t] - s;  // exclusive prefix of this thread's chunk
#pragma unroll
    for (int i = 0; i < 8; i++) { orw[t * 8 + i] = base; base += loc[i]; }
    if (t == 0) {
        int acc = 0;
        for (int j = 0; j < 64; j++) { off_clu[g * CC + j] = acc; acc += lclu[j]; }
    }
}

// ---------------- fill: CSR edge buckets + cluster->row lists ----------------
__global__ __launch_bounds__(256) void fill_kernel(const int* __restrict__ d_rows,
                                                   const int* __restrict__ d_cols,
                                                   const float* __restrict__ d_vals,
                                                   const int* __restrict__ d_index,
                                                   const int* __restrict__ off_row,
                                                   int* __restrict__ fill_row,
                                                   const int* __restrict__ off_clu,
                                                   int* __restrict__ fill_clu,
                                                   int2* __restrict__ epack,
                                                   int* __restrict__ rlist) {
    int tid = blockIdx.x * 256 + threadIdx.x;
    if (tid < BG * NNZE) {
        int g = tid >> 15;
        int r = d_rows[tid];
        int slot = atomicAdd(&fill_row[(g << 11) + r], 1);
        int p = (g << 15) + off_row[(g << 11) + r] + slot;
        epack[p] = make_int2(d_cols[tid], __float_as_int(d_vals[tid]));
    } else {
        int i = tid - BG * NNZE;
        if (i < BG * MM) {
            int g = i >> 11;
            int r = i & (MM - 1);
            int c = d_index[i];
            int slot = atomicAdd(&fill_clu[(g << 6) + c], 1);
            rlist[(g << 11) + off_clu[(g << 6) + c] + slot] = r;
        }
    }
}

// ---------------- fused SpMM + mean/max/sum pooling -> x_dec [B*C, 384] ----------------
__global__ __launch_bounds__(128) void spmm_pool_kernel(const float* __restrict__ x,
                                                        const int* __restrict__ cnt_row,
                                                        const int* __restrict__ off_row,
                                                        const int* __restrict__ cnt_clu,
                                                        const int* __restrict__ off_clu,
                                                        const int2* __restrict__ epack,
                                                        const int* __restrict__ rlist,
                                                        float* __restrict__ xdec) {
    // XCD-aware swizzle: bid&7 -> XCD (round-robin dispatch), 8 graphs per XCD for L2 locality
    int bid = blockIdx.x;
    int l = bid >> 3;
    int g = ((bid & 7) << 3) + (l >> 6);
    int c = l & 63;
    int h = threadIdx.x;
    int gc = (g << 6) + c;
    int rcnt = cnt_clu[gc];
    int rbase = (g << 11) + off_clu[gc];
    const float* xg = x + ((size_t)g << 18);  // g*N*H
    float sum = 0.0f, mx = -__builtin_inff();
    for (int i = 0; i < rcnt; i++) {
        int r = rlist[rbase + i];
        int eb = (g << 15) + off_row[(g << 11) + r];
        int ec = cnt_row[(g << 11) + r];
        float coef = 0.0f;
        for (int e = 0; e < ec; e++) {
            int2 pv = epack[eb + e];
            coef = fmaf(__int_as_float(pv.y), xg[((size_t)pv.x << 7) + h], coef);
        }
        sum += coef;
        mx = fmaxf(mx, coef);
    }
    float mean = sum / (float)(rcnt > 0 ? rcnt : 1);
    float* xd = xdec + (size_t)gc * TH;
    xd[h] = mean;
    xd[HH + h] = mx;
    xd[2 * HH + h] = sum;
}

// ---------------- QKV projection: [4096,384] @ [384,384] -> QKV [4096,384] ----------------
__global__ __launch_bounds__(256) void qkv_kernel(const float* __restrict__ xdec,
                                                  const float* __restrict__ Wq,
                                                  const float* __restrict__ Wk,
                                                  const float* __restrict__ Wv,
                                                  float* __restrict__ QKV) {
    __shared__ float As[16][68];  // A^T tile: [k][row], pad avoids bank conflicts
    __shared__ float Bs[16][64];  // [k][col]
    int bx = blockIdx.x, by = blockIdx.y;
    int t = threadIdx.x;
    int tx = t & 15, ty = t >> 4;
    const float* W = (by < 2) ? Wq : (by < 4) ? Wk : Wv;
    int cbase = (by & 1) * 64;
    int r0 = bx * 64;
    float acc[4][4] = {};
    int lrow = t >> 2, lk4 = (t & 3) * 4;
    for (int k0 = 0; k0 < TH; k0 += 16) {
        float4 av = *(const float4*)&xdec[(size_t)(r0 + lrow) * TH + k0 + lk4];
        As[lk4][lrow] = av.x;
        As[lk4 + 1][lrow] = av.y;
        As[lk4 + 2][lrow] = av.z;
        As[lk4 + 3][lrow] = av.w;
        *(float4*)&Bs[ty][tx * 4] = *(const float4*)&W[(size_t)(k0 + ty) * HH + cbase + tx * 4];
        __syncthreads();
#pragma unroll
        for (int k = 0; k < 16; k++) {
            float4 a = *(float4*)&As[k][ty * 4];
            float4 b = *(float4*)&Bs[k][tx * 4];
            float ar[4] = {a.x, a.y, a.z, a.w};
            float br[4] = {b.x, b.y, b.z, b.w};
#pragma unroll
            for (int i = 0; i < 4; i++)
#pragma unroll
                for (int j = 0; j < 4; j++) acc[i][j] = fmaf(ar[i], br[j], acc[i][j]);
        }
        __syncthreads();
    }
#pragma unroll
    for (int i = 0; i < 4; i++) {
        *(float4*)&QKV[(size_t)(r0 + ty * 4 + i) * TH + by * 64 + tx * 4] =
            make_float4(acc[i][0], acc[i][1], acc[i][2], acc[i][3]);
    }
}

// ---------------- per-graph 64x64 attention ----------------
__global__ __launch_bounds__(256) void attn_kernel(const float* __restrict__ QKV,
                                                   float* __restrict__ out) {
    __shared__ float Qs[16][132];
    __shared__ float sc[16][68];
    int g = blockIdx.x;
    int q0 = blockIdx.y * 16;
    int t = threadIdx.x;
    const float* base = QKV + (size_t)(g * CC) * TH;
    for (int u = t; u < 512; u += 256) {
        int i = u >> 5, cc = u & 31;
        *(float4*)&Qs[i][cc * 4] = *(const float4*)&base[(size_t)(q0 + i) * TH + cc * 4];
    }
    __syncthreads();
    {  // scores: thread (iq, j) computes rows iq, iq+4, iq+8, iq+12 vs col j
        int j = t & 63, iq = t >> 6;
        float a0 = 0, a1 = 0, a2 = 0, a3 = 0;
        const float* Krow = base + (size_t)j * TH + HH;
#pragma unroll 4
        for (int cc = 0; cc < 32; cc++) {
            float4 kv = *(const float4*)&Krow[cc * 4];
            float4 q0v = *(float4*)&Qs[iq][cc * 4];
            float4 q1v = *(float4*)&Qs[4 + iq][cc * 4];
            float4 q2v = *(float4*)&Qs[8 + iq][cc * 4];
            float4 q3v = *(float4*)&Qs[12 + iq][cc * 4];
            a0 += kv.x * q0v.x + kv.y * q0v.y + kv.z * q0v.z + kv.w * q0v.w;
            a1 += kv.x * q1v.x + kv.y * q1v.y + kv.z * q1v.z + kv.w * q1v.w;
            a2 += kv.x * q2v.x + kv.y * q2v.y + kv.z * q2v.z + kv.w * q2v.w;
            a3 += kv.x * q3v.x + kv.y * q3v.y + kv.z * q3v.z + kv.w * q3v.w;
        }
        const float scale = 0.08838834764831845f;  // 1/sqrt(128)
        sc[iq][j] = a0 * scale;
        sc[4 + iq][j] = a1 * scale;
        sc[8 + iq][j] = a2 * scale;
        sc[12 + iq][j] = a3 * scale;
    }
    __syncthreads();
    {  // softmax: 16 threads per row, 4 cols each
        int i = t >> 4, l = t & 15;
        float4 sv = *(float4*)&sc[i][l * 4];
        float m = fmaxf(fmaxf(sv.x, sv.y), fmaxf(sv.z, sv.w));
#pragma unroll
        for (int d = 1; d < 16; d <<= 1) m = fmaxf(m, __shfl_xor(m, d));
        float4 p;
        p.x = __expf(sv.x - m);
        p.y = __expf(sv.y - m);
        p.z = __expf(sv.z - m);
        p.w = __expf(sv.w - m);
        float s = p.x + p.y + p.z + p.w;
#pragma unroll
        for (int d = 1; d < 16; d <<= 1) s += __shfl_xor(s, d);
        float inv = 1.0f / s;
        p.x *= inv; p.y *= inv; p.z *= inv; p.w *= inv;
        *(float4*)&sc[i][l * 4] = p;
    }
    __syncthreads();
    {  // PV: thread (i, hq) computes out[i][hq*8 .. +8)
        int i = t >> 4, hq = t & 15;
        const float* Vbase = base + 2 * HH;
        float acc[8] = {};
        for (int j = 0; j < 64; j++) {
            float d = sc[i][j];
            float4 v0 = *(const float4*)&Vbase[(size_t)j * TH + hq * 8];
            float4 v1 = *(const float4*)&Vbase[(size_t)j * TH + hq * 8 + 4];
            acc[0] = fmaf(d, v0.x, acc[0]);
            acc[1] = fmaf(d, v0.y, acc[1]);
            acc[2] = fmaf(d, v0.z, acc[2]);
            acc[3] = fmaf(d, v0.w, acc[3]);
            acc[4] = fmaf(d, v1.x, acc[4]);
            acc[5] = fmaf(d, v1.y, acc[5]);
            acc[6] = fmaf(d, v1.w * 0.0f + v1.z, acc[6]);
            acc[7] = fmaf(d, v1.w, acc[7]);
        }
        float* op = out + (size_t)g * (CC * HH) + (size_t)(q0 + i) * HH + hq * 8;
        *(float4*)&op[0] = make_float4(acc[0], acc[1], acc[2], acc[3]);
        *(float4*)&op[4] = make_float4(acc[4], acc[5], acc[6], acc[7]);
    }
}

extern "C" void kernel_launch(void* const* d_in, const int* in_sizes, int n_in,
                              void* d_out, int out_size, void* d_ws, size_t ws_size,
                              hipStream_t stream) {
    const float* x = (const float*)d_in[0];
    // d_in[1] = batch (unused: nodes sorted, equal graph sizes), d_in[2] = batch_size (compile-time 64)
    const int* d_rows = (const int*)d_in[3];
    const int* d_cols = (const int*)d_in[4];
    const float* d_vals = (const float*)d_in[5];
    const int* d_index = (const int*)d_in[6];
    const float* Wq = (const float*)d_in[7];
    const float* Wk = (const float*)d_in[8];
    const float* Wv = (const float*)d_in[9];
    float* out = (float*)d_out;

    char* ws = (char*)d_ws;
    size_t o = 0;
    int* cnt_row = (int*)(ws + o); o += (size_t)BG * MM * 4;
    int* fill_row = (int*)(ws + o); o += (size_t)BG * MM * 4;
    int* cnt_clu = (int*)(ws + o); o += (size_t)BG * CC * 4;
    int* fill_clu = (int*)(ws + o); o += (size_t)BG * CC * 4;
    size_t zero_bytes = o;
    int* off_row = (int*)(ws + o); o += (size_t)BG * MM * 4;
    int* off_clu = (int*)(ws + o); o += (size_t)BG * CC * 4;
    int2* epack = (int2*)(ws + o); o += (size_t)BG * NNZE * 8;
    int* rlist = (int*)(ws + o); o += (size_t)BG * MM * 4;
    float* xdec = (float*)(ws + o); o += (size_t)BG * CC * TH * 4;
    float* QKV = (float*)(ws + o); o += (size_t)BG * CC * TH * 4;

    hipMemsetAsync(cnt_row, 0, zero_bytes, stream);
    int total = BG * NNZE + BG * MM;
    count_kernel<<<(total + 255) / 256, 256, 0, stream>>>(d_rows, d_index, cnt_row, cnt_clu);
    scan_kernel<<<BG, 256, 0, stream>>>(cnt_row, off_row, cnt_clu, off_clu);
    fill_kernel<<<(total + 255) / 256, 256, 0, stream>>>(d_rows, d_cols, d_vals, d_index,
                                                         off_row, fill_row, off_clu, fill_clu,
                                                         epack, rlist);
    spmm_pool_kernel<<<BG * CC, 128, 0, stream>>>(x, cnt_row, off_row, cnt_clu, off_clu,
                                                  epack, rlist, xdec);
    qkv_kernel<<<dim3(64, 6), 256, 0, stream>>>(xdec, Wq, Wk, Wv, QKV);
    attn_kernel<<<dim3(BG, 4), 256, 0, stream>>>(QKV, out);
}

// Round 2
// 421.838 us; speedup vs baseline: 1.4533x; 1.4533x over previous
//
#include <hip/hip_runtime.h>

#define BG 64
#define NN 2048
#define MM 2048
#define CC 64
#define HH 128
#define NNZE 32768
#define TH 384  // 3*H

// ---------------- count: edges per (g,row), rows per (g,cluster) ----------------
__global__ __launch_bounds__(256) void count_kernel(const int* __restrict__ d_rows,
                                                    const int* __restrict__ d_index,
                                                    int* __restrict__ cnt_row,
                                                    int* __restrict__ cnt_clu) {
    int tid = blockIdx.x * 256 + threadIdx.x;
    if (tid < BG * NNZE) {
        int g = tid >> 15;  // NNZ = 2^15
        atomicAdd(&cnt_row[(g << 11) + d_rows[tid]], 1);
    } else {
        int i = tid - BG * NNZE;
        if (i < BG * MM) {
            int g = i >> 11;  // M = 2^11
            atomicAdd(&cnt_clu[(g << 6) + d_index[i]], 1);
        }
    }
}

// ---------------- per-graph scan of cluster counts (64 vals, 1 wave) ----------------
__global__ __launch_bounds__(64) void scan_clu_kernel(const int* __restrict__ cnt_clu,
                                                      int* __restrict__ off_clu) {
    int g = blockIdx.x, t = threadIdx.x;
    int v = cnt_clu[(g << 6) + t];
    int incl = v;
#pragma unroll
    for (int d = 1; d < 64; d <<= 1) {
        int u = __shfl_up(incl, d);
        if (t >= d) incl += u;
    }
    off_clu[(g << 6) + t] = incl - v;
}

// ---------------- fill rlist: rows in cluster-major order ----------------
__global__ __launch_bounds__(256) void fill_rlist_kernel(const int* __restrict__ d_index,
                                                         const int* __restrict__ off_clu,
                                                         int* __restrict__ fill_clu,
                                                         int* __restrict__ rlist) {
    int tid = blockIdx.x * 256 + threadIdx.x;
    if (tid < BG * MM) {
        int g = tid >> 11;
        int r = tid & (MM - 1);
        int c = d_index[tid];
        int slot = atomicAdd(&fill_clu[(g << 6) + c], 1);
        rlist[(g << 11) + off_clu[(g << 6) + c] + slot] = r;
    }
}

// ---------------- per-graph scan of per-row edge counts IN CLUSTER-MAJOR ORDER ----------------
__global__ __launch_bounds__(256) void scan_edge_kernel(const int* __restrict__ cnt_row,
                                                        const int* __restrict__ rlist,
                                                        int* __restrict__ row_edge_off,
                                                        int* __restrict__ edge_off_by_row) {
    __shared__ int lsum[256];
    int g = blockIdx.x, t = threadIdx.x;
    int rr[8], loc[8];
    int s = 0;
#pragma unroll
    for (int i = 0; i < 8; i++) {
        rr[i] = rlist[(g << 11) + t * 8 + i];
        loc[i] = cnt_row[(g << 11) + rr[i]];
        s += loc[i];
    }
    lsum[t] = s;
    __syncthreads();
    for (int d = 1; d < 256; d <<= 1) {
        int v = (t >= d) ? lsum[t - d] : 0;
        __syncthreads();
        lsum[t] += v;
        __syncthreads();
    }
    int base = lsum[t] - s;  // exclusive prefix of this thread's chunk
    int* reo = row_edge_off + g * (MM + 1);
#pragma unroll
    for (int i = 0; i < 8; i++) {
        reo[t * 8 + i] = base;
        edge_off_by_row[(g << 11) + rr[i]] = base;
        base += loc[i];
    }
    if (t == 255) reo[MM] = NNZE;
}

// ---------------- fill edges into cluster-major contiguous buckets; flag last-of-row ----------------
__global__ __launch_bounds__(256) void fill_edge_kernel(const int* __restrict__ d_rows,
                                                        const int* __restrict__ d_cols,
                                                        const float* __restrict__ d_vals,
                                                        const int* __restrict__ cnt_row,
                                                        int* __restrict__ fill_row,
                                                        const int* __restrict__ edge_off_by_row,
                                                        int2* __restrict__ epack) {
    int tid = blockIdx.x * 256 + threadIdx.x;
    if (tid < BG * NNZE) {
        int g = tid >> 15;
        int r = d_rows[tid];
        int gr = (g << 11) + r;
        int slot = atomicAdd(&fill_row[gr], 1);
        int flag = (slot == cnt_row[gr] - 1) ? (int)0x80000000 : 0;
        int p = (g << 15) + edge_off_by_row[gr] + slot;
        epack[p] = make_int2(d_cols[tid] | flag, __float_as_int(d_vals[tid]));
    }
}

// ---------------- fused SpMM + mean/max/sum pooling, streaming edges -> x_dec [B*C, 384] ----------------
__global__ __launch_bounds__(128) void spmm_pool_kernel(const float* __restrict__ x,
                                                        const int* __restrict__ cnt_clu,
                                                        const int* __restrict__ off_clu,
                                                        const int* __restrict__ row_edge_off,
                                                        const int2* __restrict__ epack,
                                                        float* __restrict__ xdec) {
    // XCD-aware swizzle: bid&7 -> XCD (round-robin dispatch), 8 graphs per XCD for L2 locality
    int bid = blockIdx.x;
    int l = bid >> 3;
    int g = ((bid & 7) << 3) + (l >> 6);
    int c = l & 63;
    int h = threadIdx.x;
    int gc = (g << 6) + c;
    int rcnt = cnt_clu[gc];
    int j0 = off_clu[gc];
    const int* reo = row_edge_off + g * (MM + 1) + j0;
    int ebase = reo[0];
    int etot = reo[rcnt] - ebase;
    const int2* ep = epack + ((size_t)g << 15) + ebase;
    const float* xg = x + ((size_t)g << 18);  // g*N*H
    float coef = 0.0f, sum = 0.0f, mx = -__builtin_inff();
    int e = 0;
    for (; e + 8 <= etot; e += 8) {
        int2 p[8];
#pragma unroll
        for (int k = 0; k < 8; k++) p[k] = ep[e + k];
        float xv[8];
#pragma unroll
        for (int k = 0; k < 8; k++) xv[k] = xg[((size_t)(p[k].x & 0x7FFFFFFF) << 7) + h];
#pragma unroll
        for (int k = 0; k < 8; k++) {
            coef = fmaf(__int_as_float(p[k].y), xv[k], coef);
            if (p[k].x < 0) {  // wave-uniform branch (all lanes load same edge)
                sum += coef;
                mx = fmaxf(mx, coef);
                coef = 0.0f;
            }
        }
    }
    for (; e < etot; e++) {
        int2 pv = ep[e];
        coef = fmaf(__int_as_float(pv.y), xg[((size_t)(pv.x & 0x7FFFFFFF) << 7) + h], coef);
        if (pv.x < 0) {
            sum += coef;
            mx = fmaxf(mx, coef);
            coef = 0.0f;
        }
    }
    // rows with zero edges have coef==0 and must participate in max
    __shared__ int zflag;
    if (h == 0) zflag = 0;
    __syncthreads();
    int az = 0;
    for (int j = h; j < rcnt; j += 128) az |= (reo[j + 1] == reo[j]);
    if (az) zflag = 1;
    __syncthreads();
    if (zflag) mx = fmaxf(mx, 0.0f);
    float mean = sum / (float)(rcnt > 0 ? rcnt : 1);
    float* xd = xdec + (size_t)gc * TH;
    xd[h] = mean;
    xd[HH + h] = mx;
    xd[2 * HH + h] = sum;
}

// ---------------- QKV projection: [4096,384] @ [384,384] -> QKV [4096,384] ----------------
__global__ __launch_bounds__(256) void qkv_kernel(const float* __restrict__ xdec,
                                                  const float* __restrict__ Wq,
                                                  const float* __restrict__ Wk,
                                                  const float* __restrict__ Wv,
                                                  float* __restrict__ QKV) {
    __shared__ float As[16][68];  // A^T tile: [k][row], pad avoids bank conflicts
    __shared__ float Bs[16][64];  // [k][col]
    int bx = blockIdx.x, by = blockIdx.y;
    int t = threadIdx.x;
    int tx = t & 15, ty = t >> 4;
    const float* W = (by < 2) ? Wq : (by < 4) ? Wk : Wv;
    int cbase = (by & 1) * 64;
    int r0 = bx * 64;
    float acc[4][4] = {};
    int lrow = t >> 2, lk4 = (t & 3) * 4;
    for (int k0 = 0; k0 < TH; k0 += 16) {
        float4 av = *(const float4*)&xdec[(size_t)(r0 + lrow) * TH + k0 + lk4];
        As[lk4][lrow] = av.x;
        As[lk4 + 1][lrow] = av.y;
        As[lk4 + 2][lrow] = av.z;
        As[lk4 + 3][lrow] = av.w;
        *(float4*)&Bs[ty][tx * 4] = *(const float4*)&W[(size_t)(k0 + ty) * HH + cbase + tx * 4];
        __syncthreads();
#pragma unroll
        for (int k = 0; k < 16; k++) {
            float4 a = *(float4*)&As[k][ty * 4];
            float4 b = *(float4*)&Bs[k][tx * 4];
            float ar[4] = {a.x, a.y, a.z, a.w};
            float br[4] = {b.x, b.y, b.z, b.w};
#pragma unroll
            for (int i = 0; i < 4; i++)
#pragma unroll
                for (int j = 0; j < 4; j++) acc[i][j] = fmaf(ar[i], br[j], acc[i][j]);
        }
        __syncthreads();
    }
#pragma unroll
    for (int i = 0; i < 4; i++) {
        *(float4*)&QKV[(size_t)(r0 + ty * 4 + i) * TH + by * 64 + tx * 4] =
            make_float4(acc[i][0], acc[i][1], acc[i][2], acc[i][3]);
    }
}

// ---------------- per-graph 64x64 attention ----------------
__global__ __launch_bounds__(256) void attn_kernel(const float* __restrict__ QKV,
                                                   float* __restrict__ out) {
    __shared__ float Qs[16][132];
    __shared__ float sc[16][68];
    int g = blockIdx.x;
    int q0 = blockIdx.y * 16;
    int t = threadIdx.x;
    const float* base = QKV + (size_t)(g * CC) * TH;
    for (int u = t; u < 512; u += 256) {
        int i = u >> 5, cc = u & 31;
        *(float4*)&Qs[i][cc * 4] = *(const float4*)&base[(size_t)(q0 + i) * TH + cc * 4];
    }
    __syncthreads();
    {  // scores: thread (iq, j) computes rows iq, iq+4, iq+8, iq+12 vs col j
        int j = t & 63, iq = t >> 6;
        float a0 = 0, a1 = 0, a2 = 0, a3 = 0;
        const float* Krow = base + (size_t)j * TH + HH;
#pragma unroll 4
        for (int cc = 0; cc < 32; cc++) {
            float4 kv = *(const float4*)&Krow[cc * 4];
            float4 q0v = *(float4*)&Qs[iq][cc * 4];
            float4 q1v = *(float4*)&Qs[4 + iq][cc * 4];
            float4 q2v = *(float4*)&Qs[8 + iq][cc * 4];
            float4 q3v = *(float4*)&Qs[12 + iq][cc * 4];
            a0 += kv.x * q0v.x + kv.y * q0v.y + kv.z * q0v.z + kv.w * q0v.w;
            a1 += kv.x * q1v.x + kv.y * q1v.y + kv.z * q1v.z + kv.w * q1v.w;
            a2 += kv.x * q2v.x + kv.y * q2v.y + kv.z * q2v.z + kv.w * q2v.w;
            a3 += kv.x * q3v.x + kv.y * q3v.y + kv.z * q3v.z + kv.w * q3v.w;
        }
        const float scale = 0.08838834764831845f;  // 1/sqrt(128)
        sc[iq][j] = a0 * scale;
        sc[4 + iq][j] = a1 * scale;
        sc[8 + iq][j] = a2 * scale;
        sc[12 + iq][j] = a3 * scale;
    }
    __syncthreads();
    {  // softmax: 16 threads per row, 4 cols each
        int i = t >> 4, l = t & 15;
        float4 sv = *(float4*)&sc[i][l * 4];
        float m = fmaxf(fmaxf(sv.x, sv.y), fmaxf(sv.z, sv.w));
#pragma unroll
        for (int d = 1; d < 16; d <<= 1) m = fmaxf(m, __shfl_xor(m, d));
        float4 p;
        p.x = __expf(sv.x - m);
        p.y = __expf(sv.y - m);
        p.z = __expf(sv.z - m);
        p.w = __expf(sv.w - m);
        float s = p.x + p.y + p.z + p.w;
#pragma unroll
        for (int d = 1; d < 16; d <<= 1) s += __shfl_xor(s, d);
        float inv = 1.0f / s;
        p.x *= inv; p.y *= inv; p.z *= inv; p.w *= inv;
        *(float4*)&sc[i][l * 4] = p;
    }
    __syncthreads();
    {  // PV: thread (i, hq) computes out[i][hq*8 .. +8)
        int i = t >> 4, hq = t & 15;
        const float* Vbase = base + 2 * HH;
        float acc[8] = {};
        for (int j = 0; j < 64; j++) {
            float d = sc[i][j];
            float4 v0 = *(const float4*)&Vbase[(size_t)j * TH + hq * 8];
            float4 v1 = *(const float4*)&Vbase[(size_t)j * TH + hq * 8 + 4];
            acc[0] = fmaf(d, v0.x, acc[0]);
            acc[1] = fmaf(d, v0.y, acc[1]);
            acc[2] = fmaf(d, v0.z, acc[2]);
            acc[3] = fmaf(d, v0.w, acc[3]);
            acc[4] = fmaf(d, v1.x, acc[4]);
            acc[5] = fmaf(d, v1.y, acc[5]);
            acc[6] = fmaf(d, v1.z, acc[6]);
            acc[7] = fmaf(d, v1.w, acc[7]);
        }
        float* op = out + (size_t)g * (CC * HH) + (size_t)(q0 + i) * HH + hq * 8;
        *(float4*)&op[0] = make_float4(acc[0], acc[1], acc[2], acc[3]);
        *(float4*)&op[4] = make_float4(acc[4], acc[5], acc[6], acc[7]);
    }
}

extern "C" void kernel_launch(void* const* d_in, const int* in_sizes, int n_in,
                              void* d_out, int out_size, void* d_ws, size_t ws_size,
                              hipStream_t stream) {
    const float* x = (const float*)d_in[0];
    // d_in[1] = batch (unused: nodes sorted, equal graph sizes), d_in[2] = batch_size (compile-time 64)
    const int* d_rows = (const int*)d_in[3];
    const int* d_cols = (const int*)d_in[4];
    const float* d_vals = (const float*)d_in[5];
    const int* d_index = (const int*)d_in[6];
    const float* Wq = (const float*)d_in[7];
    const float* Wk = (const float*)d_in[8];
    const float* Wv = (const float*)d_in[9];
    float* out = (float*)d_out;

    char* ws = (char*)d_ws;
    size_t o = 0;
    int* cnt_row = (int*)(ws + o); o += (size_t)BG * MM * 4;
    int* fill_row = (int*)(ws + o); o += (size_t)BG * MM * 4;
    int* cnt_clu = (int*)(ws + o); o += (size_t)BG * CC * 4;
    int* fill_clu = (int*)(ws + o); o += (size_t)BG * CC * 4;
    size_t zero_bytes = o;
    int* off_clu = (int*)(ws + o); o += (size_t)BG * CC * 4;
    int* rlist = (int*)(ws + o); o += (size_t)BG * MM * 4;
    int* row_edge_off = (int*)(ws + o); o += (size_t)BG * (MM + 1) * 4;
    int* edge_off_by_row = (int*)(ws + o); o += (size_t)BG * MM * 4;
    int2* epack = (int2*)(ws + o); o += (size_t)BG * NNZE * 8;
    float* xdec = (float*)(ws + o); o += (size_t)BG * CC * TH * 4;
    float* QKV = (float*)(ws + o); o += (size_t)BG * CC * TH * 4;

    hipMemsetAsync(cnt_row, 0, zero_bytes, stream);
    int total = BG * NNZE + BG * MM;
    count_kernel<<<(total + 255) / 256, 256, 0, stream>>>(d_rows, d_index, cnt_row, cnt_clu);
    scan_clu_kernel<<<BG, 64, 0, stream>>>(cnt_clu, off_clu);
    fill_rlist_kernel<<<(BG * MM + 255) / 256, 256, 0, stream>>>(d_index, off_clu, fill_clu, rlist);
    scan_edge_kernel<<<BG, 256, 0, stream>>>(cnt_row, rlist, row_edge_off, edge_off_by_row);
    fill_edge_kernel<<<(BG * NNZE + 255) / 256, 256, 0, stream>>>(d_rows, d_cols, d_vals,
                                                                  cnt_row, fill_row,
                                                                  edge_off_by_row, epack);
    spmm_pool_kernel<<<BG * CC, 128, 0, stream>>>(x, cnt_clu, off_clu, row_edge_off, epack, xdec);
    qkv_kernel<<<dim3(64, 6), 256, 0, stream>>>(xdec, Wq, Wk, Wv, QKV);
    attn_kernel<<<dim3(BG, 4), 256, 0, stream>>>(QKV, out);
}